// Round 3
// baseline (1791.579 us; speedup 1.0000x reference)
//
#include <hip/hip_runtime.h>

#define NN 50000
#define EE 1600000
// IN=128, HID=32, OUT=64, ED=64, H=4, HC=128

__device__ inline float b2f(unsigned short u) {
    return __uint_as_float(((unsigned)u) << 16);
}
__device__ inline float blo(unsigned u) { return __uint_as_float(u << 16); }
__device__ inline float bhi(unsigned u) { return __uint_as_float(u & 0xffff0000u); }
__device__ inline unsigned short f2bf(float f) {
    unsigned u = __float_as_uint(f);
    unsigned r = 0x7fffu + ((u >> 16) & 1u);
    return (unsigned short)((u + r) >> 16);
}
__device__ inline unsigned pk2(float a, float b) {
    return (unsigned)f2bf(a) | ((unsigned)f2bf(b) << 16);
}
__device__ inline void stv(float* p, size_t i, float v) { p[i] = v; }
__device__ inline void stv(unsigned short* p, size_t i, float v) { p[i] = f2bf(v); }

// ---------------- dtype sniffer: is input f32 (1) or bf16 (0)? ----------------
__global__ void sniff_kernel(const void* w, int* flags) {
    int lane = threadIdx.x;
    const unsigned short* u = (const unsigned short*)w;
    int bad = 0;
    for (int i = lane; i < 256; i += 64) {
        float f = b2f(u[i]);
        if (!(fabsf(f) < 2.0f)) bad++;  // catches big values AND NaN
    }
    unsigned long long m = __ballot(bad > 0);
    if (lane == 0) {
        flags[0] = (__popcll(m) > 8) ? 1 : 0;  // 1 = inputs are f32
        flags[1] = 0;                          // constant "bf16" flag
    }
}

// ---------------- canonicalize all weights/biases to bf16 in ws ----------------
struct WTab {
    const void* p[18];
    int off[18];
    int sz[18];
};
__global__ void __launch_bounds__(256) convert_kernel(WTab t, const int* __restrict__ flags,
                                                      unsigned short* __restrict__ dst) {
    int f32 = flags[0];
    int ti = blockIdx.y;
    int i = blockIdx.x * 256 + threadIdx.x;
    if (i < t.sz[ti]) {
        dst[t.off[ti] + i] = f32 ? f2bf(((const float*)t.p[ti])[i])
                                 : ((const unsigned short*)t.p[ti])[i];
    }
}

// ---------------- CSR build ----------------
__global__ void __launch_bounds__(256) count_kernel(const int* __restrict__ dst,
                                                    int* __restrict__ cnt) {
    int e = blockIdx.x * 256 + threadIdx.x;
    if (e < EE) atomicAdd(&cnt[dst[e]], 1);
}

__global__ void __launch_bounds__(1024) scan_kernel(int* __restrict__ cntfill,
                                                    int* __restrict__ rowptr) {
    __shared__ int s[1024];
    __shared__ int carry_s;
    int tid = threadIdx.x;
    if (tid == 0) carry_s = 0;
    __syncthreads();
    for (int base = 0; base < NN; base += 4096) {
        int i0 = base + tid * 4;
        int v0 = (i0 + 0 < NN) ? cntfill[i0 + 0] : 0;
        int v1 = (i0 + 1 < NN) ? cntfill[i0 + 1] : 0;
        int v2 = (i0 + 2 < NN) ? cntfill[i0 + 2] : 0;
        int v3 = (i0 + 3 < NN) ? cntfill[i0 + 3] : 0;
        int tsum = v0 + v1 + v2 + v3;
        s[tid] = tsum;
        __syncthreads();
        for (int off = 1; off < 1024; off <<= 1) {
            int t = (tid >= off) ? s[tid - off] : 0;
            __syncthreads();
            s[tid] += t;
            __syncthreads();
        }
        int carry = carry_s;
        int excl = carry + s[tid] - tsum;
        int e0 = excl, e1 = excl + v0, e2 = e1 + v1, e3 = e2 + v2;
        if (i0 + 0 < NN) { rowptr[i0 + 0] = e0; cntfill[i0 + 0] = e0; }
        if (i0 + 1 < NN) { rowptr[i0 + 1] = e1; cntfill[i0 + 1] = e1; }
        if (i0 + 2 < NN) { rowptr[i0 + 2] = e2; cntfill[i0 + 2] = e2; }
        if (i0 + 3 < NN) { rowptr[i0 + 3] = e3; cntfill[i0 + 3] = e3; }
        __syncthreads();
        if (tid == 1023) carry_s = carry + s[1023];
        __syncthreads();
    }
    if (tid == 0) rowptr[NN] = carry_s;
}

__global__ void __launch_bounds__(256) fill_kernel(const int* __restrict__ dst,
                                                   int* __restrict__ cntfill,
                                                   int* __restrict__ perm) {
    int e = blockIdx.x * 256 + threadIdx.x;
    if (e < EE) {
        int p = atomicAdd(&cntfill[dst[e]], 1);
        perm[p] = e;
    }
}

// ---------------- node GEMM: C[nrows,OD] = X[nrows,K] @ W[K,OD] + b ----------------
// LAYOUT 0: idx = rr*ldc + c*cstride + coff
// LAYOUT 3 (v1 pack, OD=128): lane=(c>>5)*16+(c&15) owns packed pair (c, c+16):
//   ushort idx = rr*128 + lane*2 + ((c&31)>>4)
template <typename TO, int K, int OD, int TR, int LAYOUT = 0>
__global__ void __launch_bounds__(256) gemm_node(const void* __restrict__ X,
                                                 const int* __restrict__ flagp,
                                                 const unsigned short* __restrict__ W,
                                                 const unsigned short* __restrict__ bias,
                                                 TO* __restrict__ C, int nrows,
                                                 int ldc, int cstride, int coff) {
    constexpr int TRP = TR + 4;
    __shared__ unsigned short Ws[K * OD];
    __shared__ float Xs[K * TRP];
    int tid = threadIdx.x;
    int xf32 = *flagp;
    for (int i = tid; i < K * OD; i += 256) Ws[i] = W[i];
    int row0 = blockIdx.x * TR;
    const float* Xf = (const float*)X;
    const unsigned short* Xu = (const unsigned short*)X;
    for (int i = tid; i < TR * K; i += 256) {
        int r = i / K, kk = i % K;
        int rr = row0 + r;
        float vv = 0.f;
        if (rr < nrows) {
            size_t idx = (size_t)rr * K + kk;
            vv = xf32 ? Xf[idx] : b2f(Xu[idx]);
        }
        Xs[kk * TRP + r] = vv;
    }
    __syncthreads();
    constexpr int CG = OD / 4;
    int rg = tid / CG, cg = tid % CG;
    int r0 = rg * 4, c0 = cg * 4;
    float acc[4][4] = {};
#pragma unroll 4
    for (int kk = 0; kk < K; ++kk) {
        const float4 xv = *(const float4*)&Xs[kk * TRP + r0];
        ushort4 wu = *(const ushort4*)&Ws[kk * OD + c0];
        float xa[4] = {xv.x, xv.y, xv.z, xv.w};
        float wb[4] = {b2f(wu.x), b2f(wu.y), b2f(wu.z), b2f(wu.w)};
#pragma unroll
        for (int i2 = 0; i2 < 4; i2++)
#pragma unroll
            for (int j2 = 0; j2 < 4; j2++) acc[i2][j2] += xa[i2] * wb[j2];
    }
    float bb[4];
#pragma unroll
    for (int j2 = 0; j2 < 4; j2++) bb[j2] = b2f(bias[c0 + j2]);
#pragma unroll
    for (int i2 = 0; i2 < 4; i2++) {
        int rr = row0 + r0 + i2;
        if (rr < nrows) {
#pragma unroll
            for (int j2 = 0; j2 < 4; j2++) {
                size_t idx;
                if constexpr (LAYOUT == 0) {
                    idx = (size_t)rr * ldc + (size_t)(c0 + j2) * cstride + coff;
                } else {
                    int c = c0 + j2;
                    idx = (size_t)rr * 128 +
                          (size_t)(((c >> 5) * 16 + (c & 15)) * 2 + ((c & 31) >> 4));
                }
                stv(C, idx, acc[i2][j2] + bb[j2]);
            }
        }
    }
}

// ---------------- qe1[n, h*64+d] = sum_c q1[n,h*32+c] * We1[d, h*32+c] ----------------
__global__ void __launch_bounds__(256) qe1_kernel(const unsigned short* __restrict__ q,
                                                  const unsigned short* __restrict__ We,
                                                  float* __restrict__ qe) {
    __shared__ float Ws[64 * 129];
    __shared__ float qs[8 * 128];
    int tid = threadIdx.x;
    for (int i = tid; i < 64 * 128; i += 256) Ws[(i / 128) * 129 + (i % 128)] = b2f(We[i]);
    int n0 = blockIdx.x * 8;
    for (int i = tid; i < 8 * 128; i += 256) {
        int n = n0 + (i >> 7);
        qs[i] = (n < NN) ? b2f(q[(size_t)n * 128 + (i & 127)]) : 0.f;
    }
    __syncthreads();
    int h = tid >> 6, d = tid & 63;
    for (int nl = 0; nl < 8; ++nl) {
        int n = n0 + nl;
        if (n < NN) {
            float acc = 0.f;
#pragma unroll
            for (int c = 0; c < 32; ++c)
                acc += qs[nl * 128 + h * 32 + c] * Ws[d * 129 + h * 32 + c];
            qe[(size_t)n * 256 + h * 64 + d] = acc;
        }
    }
}

// ---------------- qe2[n,d] = sum_c q2[n,c] * We2[d,c] ----------------
__global__ void __launch_bounds__(256) qe2_kernel(const unsigned short* __restrict__ q,
                                                  const unsigned short* __restrict__ We,
                                                  float* __restrict__ qe) {
    __shared__ float Ws[64 * 65];
    __shared__ float qs[4 * 64];
    int tid = threadIdx.x;
    for (int i = tid; i < 64 * 64; i += 256) Ws[(i / 64) * 65 + (i % 64)] = b2f(We[i]);
    int n0 = blockIdx.x * 4;
    {
        int n = n0 + (tid >> 6);
        qs[tid] = (n < NN) ? b2f(q[(size_t)n * 64 + (tid & 63)]) : 0.f;
    }
    __syncthreads();
    int nl = tid >> 6, d = tid & 63;
    int n = n0 + nl;
    if (n < NN) {
        float acc = 0.f;
#pragma unroll
        for (int c = 0; c < 64; ++c) acc += qs[nl * 64 + c] * Ws[d * 65 + c];
        qe[(size_t)n * 64 + d] = acc;
    }
}

// ---------------- ega1: edge-parallel gather + alpha (layer 1) ----------------
// 16 lanes per edge: t = h*4 + s (h=head, s=quarter).
//   q·k over dims 8t..8t+7  (belongs to head t/4 == h)
//   qe·ef: head h, ef dims 16s..16s+15
// reduce over s (shfl_xor 1,2) -> alpha[i*4+h].
// Side products: src_perm[i], dst_perm[i] (IN-PLACE over perm: safe, the only
// readers of perm[i] are this wave's 16 lanes, lockstep read-before-write),
// efperm[i][64] bf16 (written by h==0 lanes from registers).
__global__ void __launch_bounds__(256) ega1_kernel(
    int* __restrict__ perm, const int* __restrict__ src, const int* __restrict__ dst,
    const void* __restrict__ efp, const int* __restrict__ flagp,
    const unsigned short* __restrict__ q, const unsigned short* __restrict__ k,
    const float* __restrict__ qe, int* __restrict__ srcp,
    unsigned short* __restrict__ efperm, float* __restrict__ alpha) {
    int ef32 = *flagp;
    int lane = threadIdx.x & 63;
    int wv = (blockIdx.x * 256 + threadIdx.x) >> 6;
    int el = lane >> 4, t = lane & 15;
    int h = t >> 2, s = t & 3;
    int i = wv * 4 + el;
    if (i >= EE) return;
    int e = perm[i];
    int sj = src[e], dj = dst[e];
    if (t == 0) {
        srcp[i] = sj;
        perm[i] = dj;  // perm becomes dst_perm
    }
    // q.k partial, dims 8t..8t+7
    uint4 qu = *(const uint4*)(q + (size_t)dj * 128 + 8 * t);
    uint4 ku = *(const uint4*)(k + (size_t)sj * 128 + 8 * t);
    float kd = blo(qu.x) * blo(ku.x) + bhi(qu.x) * bhi(ku.x) +
               blo(qu.y) * blo(ku.y) + bhi(qu.y) * bhi(ku.y) +
               blo(qu.z) * blo(ku.z) + bhi(qu.z) * bhi(ku.z) +
               blo(qu.w) * blo(ku.w) + bhi(qu.w) * bhi(ku.w);
    // ef dims 16s..16s+15
    float fv[16];
    uint4 pa, pb;
    if (ef32) {
        const float* er = (const float*)efp + (size_t)e * 64 + 16 * s;
        float4 x0 = *(const float4*)(er + 0);
        float4 x1 = *(const float4*)(er + 4);
        float4 x2 = *(const float4*)(er + 8);
        float4 x3 = *(const float4*)(er + 12);
        fv[0] = x0.x; fv[1] = x0.y; fv[2] = x0.z; fv[3] = x0.w;
        fv[4] = x1.x; fv[5] = x1.y; fv[6] = x1.z; fv[7] = x1.w;
        fv[8] = x2.x; fv[9] = x2.y; fv[10] = x2.z; fv[11] = x2.w;
        fv[12] = x3.x; fv[13] = x3.y; fv[14] = x3.z; fv[15] = x3.w;
        if (h == 0) {
            pa.x = pk2(fv[0], fv[1]); pa.y = pk2(fv[2], fv[3]);
            pa.z = pk2(fv[4], fv[5]); pa.w = pk2(fv[6], fv[7]);
            pb.x = pk2(fv[8], fv[9]); pb.y = pk2(fv[10], fv[11]);
            pb.z = pk2(fv[12], fv[13]); pb.w = pk2(fv[14], fv[15]);
        }
    } else {
        const unsigned short* er = (const unsigned short*)efp + (size_t)e * 64 + 16 * s;
        pa = *(const uint4*)er;
        pb = *(const uint4*)(er + 8);
        fv[0] = blo(pa.x); fv[1] = bhi(pa.x); fv[2] = blo(pa.y); fv[3] = bhi(pa.y);
        fv[4] = blo(pa.z); fv[5] = bhi(pa.z); fv[6] = blo(pa.w); fv[7] = bhi(pa.w);
        fv[8] = blo(pb.x); fv[9] = bhi(pb.x); fv[10] = blo(pb.y); fv[11] = bhi(pb.y);
        fv[12] = blo(pb.z); fv[13] = bhi(pb.z); fv[14] = blo(pb.w); fv[15] = bhi(pb.w);
    }
    if (h == 0) {
        *(uint4*)(efperm + (size_t)i * 64 + 16 * s) = pa;
        *(uint4*)(efperm + (size_t)i * 64 + 16 * s + 8) = pb;
    }
    const float* qr = qe + (size_t)dj * 256 + h * 64 + 16 * s;
    float ed = 0.f;
#pragma unroll
    for (int j = 0; j < 16; ++j) ed += fv[j] * qr[j];
    float part = kd + ed;
    part += __shfl_xor(part, 1);
    part += __shfl_xor(part, 2);
    if (s == 0) alpha[(size_t)i * 4 + h] = part * 0.17677669529663687f;  // 1/sqrt(32)
}

// ---------------- ega2: edge-parallel alpha (layer 2, H=1, C=64) ----------------
__global__ void __launch_bounds__(256) ega2_kernel(
    const int* __restrict__ srcp, const int* __restrict__ dstp,
    const unsigned short* __restrict__ q, const unsigned short* __restrict__ k,
    const float* __restrict__ qe, const unsigned short* __restrict__ efperm,
    float* __restrict__ alpha) {
    int lane = threadIdx.x & 63;
    int wv = (blockIdx.x * 256 + threadIdx.x) >> 6;
    int el = lane >> 4, t = lane & 15;
    int i = wv * 4 + el;
    if (i >= EE) return;
    int sj = srcp[i], dj = dstp[i];
    uint2 qu = *(const uint2*)(q + (size_t)dj * 64 + 4 * t);
    uint2 ku = *(const uint2*)(k + (size_t)sj * 64 + 4 * t);
    uint2 fu = *(const uint2*)(efperm + (size_t)i * 64 + 4 * t);
    float4 qev = *(const float4*)(qe + (size_t)dj * 64 + 4 * t);
    float part = blo(qu.x) * blo(ku.x) + bhi(qu.x) * bhi(ku.x) +
                 blo(qu.y) * blo(ku.y) + bhi(qu.y) * bhi(ku.y) +
                 qev.x * blo(fu.x) + qev.y * bhi(fu.x) +
                 qev.z * blo(fu.y) + qev.w * bhi(fu.y);
    part += __shfl_xor(part, 1);
    part += __shfl_xor(part, 2);
    part += __shfl_xor(part, 4);
    part += __shfl_xor(part, 8);
    if (t == 0) alpha[i] = part * 0.125f;  // 1/sqrt(64)
}

// ---------------- layer1 accumulate step (4 edges, no serial deps) ----------------
__device__ __forceinline__ void acc1_step(const unsigned (&vv)[4], const ushort4 (&fu)[4],
                                          const float (&al)[4], float mh,
                                          float& l, float& a1, float& a2,
                                          float& w0, float& w1, float& w2, float& w3) {
#pragma unroll
    for (int u = 0; u < 4; ++u) {
        float w = __expf(al[u] - mh);
        l += w;
        a1 += w * blo(vv[u]);
        a2 += w * bhi(vv[u]);
        w0 += w * b2f(fu[u].x);
        w1 += w * b2f(fu[u].y);
        w2 += w * b2f(fu[u].z);
        w3 += w * b2f(fu[u].w);
    }
}

// ---------------- node_accum1: wave per node; exact-max softmax + accumulate ------
// lane = h4*16 + dq owns av dims (h4*32+dq, +16) [vpk packed] and wef dims
// h4*64+4dq..+3 [efperm ushort4].
__global__ void __launch_bounds__(256) node_accum1(
    const int* __restrict__ rowptr, const int* __restrict__ srcp,
    const float* __restrict__ alpha, const unsigned* __restrict__ vpk,
    const unsigned short* __restrict__ efperm,
    float* __restrict__ av, float* __restrict__ wef) {
    int lane = threadIdx.x & 63;
    int node = (blockIdx.x * 256 + threadIdx.x) >> 6;
    if (node >= NN) return;
    int beg = rowptr[node], end = rowptr[node + 1];
    int h4 = lane >> 4, dq = lane & 15;
    int c1 = h4 * 32 + dq, c2 = c1 + 16;
    const float NINF = -__builtin_inff();
    // pass 1: per-head max over alpha (16 edges/iter, head = lane&3)
    float mx = NINF;
    for (int i0 = beg; i0 < end; i0 += 16) {
        int idx = i0 + (lane >> 2);
        int idc = idx < end ? idx : beg;
        float a = alpha[(size_t)idc * 4 + (lane & 3)];
        mx = fmaxf(mx, idx < end ? a : NINF);
    }
    mx = fmaxf(mx, __shfl_xor(mx, 4));
    mx = fmaxf(mx, __shfl_xor(mx, 8));
    mx = fmaxf(mx, __shfl_xor(mx, 16));
    mx = fmaxf(mx, __shfl_xor(mx, 32));
    float mh = __shfl(mx, h4);  // max for head h4 (lane h4 holds head h4)
    // pass 2: accumulate (no online rescale, no shfl)
    float l = 0.f, a1 = 0.f, a2 = 0.f;
    float w0 = 0.f, w1 = 0.f, w2 = 0.f, w3 = 0.f;
    int ng = (end - beg) >> 2;
    if (ng > 0) {
        int ssA[4], ssB[4];
        unsigned vA[4], vB[4];
        ushort4 fA[4], fB[4];
        float aA[4], aB[4];
#pragma unroll
        for (int u = 0; u < 4; ++u) ssA[u] = srcp[beg + u];
#pragma unroll
        for (int u = 0; u < 4; ++u) vA[u] = vpk[(size_t)ssA[u] * 64 + lane];
#pragma unroll
        for (int u = 0; u < 4; ++u)
            fA[u] = *(const ushort4*)(efperm + (size_t)(beg + u) * 64 + 4 * dq);
#pragma unroll
        for (int u = 0; u < 4; ++u) aA[u] = alpha[(size_t)(beg + u) * 4 + h4];
        if (ng > 1) {
#pragma unroll
            for (int u = 0; u < 4; ++u) ssB[u] = srcp[beg + 4 + u];
        }
        int g = 0;
        while (true) {
            bool nextB = (g + 1 < ng);
            if (nextB) {
                int ib = beg + ((g + 1) << 2);
#pragma unroll
                for (int u = 0; u < 4; ++u) vB[u] = vpk[(size_t)ssB[u] * 64 + lane];
#pragma unroll
                for (int u = 0; u < 4; ++u)
                    fB[u] = *(const ushort4*)(efperm + (size_t)(ib + u) * 64 + 4 * dq);
#pragma unroll
                for (int u = 0; u < 4; ++u) aB[u] = alpha[(size_t)(ib + u) * 4 + h4];
                if (g + 2 < ng) {
                    int ib2 = beg + ((g + 2) << 2);
#pragma unroll
                    for (int u = 0; u < 4; ++u) ssA[u] = srcp[ib2 + u];
                }
            }
            acc1_step(vA, fA, aA, mh, l, a1, a2, w0, w1, w2, w3);
            if (!nextB) break;
            ++g;
            bool nextA = (g + 1 < ng);
            if (nextA) {
                int ib = beg + ((g + 1) << 2);
#pragma unroll
                for (int u = 0; u < 4; ++u) vA[u] = vpk[(size_t)ssA[u] * 64 + lane];
#pragma unroll
                for (int u = 0; u < 4; ++u)
                    fA[u] = *(const ushort4*)(efperm + (size_t)(ib + u) * 64 + 4 * dq);
#pragma unroll
                for (int u = 0; u < 4; ++u) aA[u] = alpha[(size_t)(ib + u) * 4 + h4];
                if (g + 2 < ng) {
                    int ib2 = beg + ((g + 2) << 2);
#pragma unroll
                    for (int u = 0; u < 4; ++u) ssB[u] = srcp[ib2 + u];
                }
            }
            acc1_step(vB, fB, aB, mh, l, a1, a2, w0, w1, w2, w3);
            if (!nextA) break;
            ++g;
        }
    }
    for (int i = beg + (ng << 2); i < end; ++i) {
        int sj = srcp[i];
        float w = __expf(alpha[(size_t)i * 4 + h4] - mh);
        unsigned vv = vpk[(size_t)sj * 64 + lane];
        ushort4 fu = *(const ushort4*)(efperm + (size_t)i * 64 + 4 * dq);
        l += w;
        a1 += w * blo(vv);
        a2 += w * bhi(vv);
        w0 += w * b2f(fu.x); w1 += w * b2f(fu.y);
        w2 += w * b2f(fu.z); w3 += w * b2f(fu.w);
    }
    float inv = (l > 0.f) ? 1.f / l : 0.f;
    av[(size_t)node * 128 + c1] = a1 * inv;
    av[(size_t)node * 128 + c2] = a2 * inv;
    float4 wout = make_float4(w0 * inv, w1 * inv, w2 * inv, w3 * inv);
    *(float4*)(wef + (size_t)node * 256 + h4 * 64 + 4 * dq) = wout;
}

// ---------------- node_accum2: wave per node (H=1, C=64) ----------------
__global__ void __launch_bounds__(256) node_accum2(
    const int* __restrict__ rowptr, const int* __restrict__ srcp,
    const float* __restrict__ alpha, const unsigned short* __restrict__ v,
    const unsigned short* __restrict__ efperm,
    float* __restrict__ av, float* __restrict__ wef) {
    int lane = threadIdx.x & 63;
    int node = (blockIdx.x * 256 + threadIdx.x) >> 6;
    if (node >= NN) return;
    int beg = rowptr[node], end = rowptr[node + 1];
    const float NINF = -__builtin_inff();
    float mx = NINF;
    for (int i0 = beg; i0 < end; i0 += 64) {
        int idx = i0 + lane;
        int idc = idx < end ? idx : beg;
        float a = alpha[idc];
        mx = fmaxf(mx, idx < end ? a : NINF);
    }
    mx = fmaxf(mx, __shfl_xor(mx, 1));
    mx = fmaxf(mx, __shfl_xor(mx, 2));
    mx = fmaxf(mx, __shfl_xor(mx, 4));
    mx = fmaxf(mx, __shfl_xor(mx, 8));
    mx = fmaxf(mx, __shfl_xor(mx, 16));
    mx = fmaxf(mx, __shfl_xor(mx, 32));
    float l = 0.f, a1 = 0.f, w0 = 0.f;
    int ng = (end - beg) >> 2;
    if (ng > 0) {
        int ssA[4], ssB[4];
        unsigned short vA[4], vB[4], fA[4], fB[4];
        float aA[4], aB[4];
#pragma unroll
        for (int u = 0; u < 4; ++u) ssA[u] = srcp[beg + u];
#pragma unroll
        for (int u = 0; u < 4; ++u) vA[u] = v[(size_t)ssA[u] * 64 + lane];
#pragma unroll
        for (int u = 0; u < 4; ++u) fA[u] = efperm[(size_t)(beg + u) * 64 + lane];
#pragma unroll
        for (int u = 0; u < 4; ++u) aA[u] = alpha[beg + u];
        if (ng > 1) {
#pragma unroll
            for (int u = 0; u < 4; ++u) ssB[u] = srcp[beg + 4 + u];
        }
        int g = 0;
        while (true) {
            bool nextB = (g + 1 < ng);
            if (nextB) {
                int ib = beg + ((g + 1) << 2);
#pragma unroll
                for (int u = 0; u < 4; ++u) vB[u] = v[(size_t)ssB[u] * 64 + lane];
#pragma unroll
                for (int u = 0; u < 4; ++u) fB[u] = efperm[(size_t)(ib + u) * 64 + lane];
#pragma unroll
                for (int u = 0; u < 4; ++u) aB[u] = alpha[ib + u];
                if (g + 2 < ng) {
                    int ib2 = beg + ((g + 2) << 2);
#pragma unroll
                    for (int u = 0; u < 4; ++u) ssA[u] = srcp[ib2 + u];
                }
            }
#pragma unroll
            for (int u = 0; u < 4; ++u) {
                float w = __expf(aA[u] - mx);
                l += w;
                a1 += w * b2f(vA[u]);
                w0 += w * b2f(fA[u]);
            }
            if (!nextB) break;
            ++g;
            bool nextA = (g + 1 < ng);
            if (nextA) {
                int ib = beg + ((g + 1) << 2);
#pragma unroll
                for (int u = 0; u < 4; ++u) vA[u] = v[(size_t)ssA[u] * 64 + lane];
#pragma unroll
                for (int u = 0; u < 4; ++u) fA[u] = efperm[(size_t)(ib + u) * 64 + lane];
#pragma unroll
                for (int u = 0; u < 4; ++u) aA[u] = alpha[ib + u];
                if (g + 2 < ng) {
                    int ib2 = beg + ((g + 2) << 2);
#pragma unroll
                    for (int u = 0; u < 4; ++u) ssB[u] = srcp[ib2 + u];
                }
            }
#pragma unroll
            for (int u = 0; u < 4; ++u) {
                float w = __expf(aB[u] - mx);
                l += w;
                a1 += w * b2f(vB[u]);
                w0 += w * b2f(fB[u]);
            }
            if (!nextA) break;
            ++g;
        }
    }
    for (int i = beg + (ng << 2); i < end; ++i) {
        int sj = srcp[i];
        float w = __expf(alpha[i] - mx);
        l += w;
        a1 += w * b2f(v[(size_t)sj * 64 + lane]);
        w0 += w * b2f(efperm[(size_t)i * 64 + lane]);
    }
    float inv = (l > 0.f) ? 1.f / l : 0.f;
    av[(size_t)node * 64 + lane] = a1 * inv;
    wef[(size_t)node * 64 + lane] = w0 * inv;
}

// ---------------- epilogue 1: h = relu(av + wef@We1 + s1), bf16 out ----------------
__global__ void __launch_bounds__(256) ep1_kernel(const float* __restrict__ av,
                                                  const float* __restrict__ wef,
                                                  const float* __restrict__ s1,
                                                  const unsigned short* __restrict__ We,
                                                  unsigned short* __restrict__ hout) {
    __shared__ float Ws[64 * 128];
    int tid = threadIdx.x;
    for (int i = tid; i < 64 * 128; i += 256) Ws[i] = b2f(We[i]);
    __syncthreads();
    int nl = tid >> 7;
    int c = tid & 127;
    int g = c >> 5;  // head
    for (int it = 0; it < 8; ++it) {
        int n = blockIdx.x * 16 + it * 2 + nl;
        if (n < NN) {
            const float* wr = wef + (size_t)n * 256 + g * 64;
            float acc = 0.f;
#pragma unroll
            for (int d = 0; d < 64; ++d) acc += wr[d] * Ws[d * 128 + c];
            float val = av[(size_t)n * 128 + c] + acc + s1[(size_t)n * 128 + c];
            hout[(size_t)n * 128 + c] = f2bf(fmaxf(val, 0.f));
        }
    }
}

// ---------------- epilogue 2: out = av2 + wef2@We2 + s2 (f32 output!) ----------------
__global__ void __launch_bounds__(256) ep2_kernel(const float* __restrict__ av,
                                                  const float* __restrict__ wef,
                                                  const float* __restrict__ s2,
                                                  const unsigned short* __restrict__ We,
                                                  float* __restrict__ out) {
    __shared__ float Ws[64 * 64];
    int tid = threadIdx.x;
    for (int i = tid; i < 64 * 64; i += 256) Ws[i] = b2f(We[i]);
    __syncthreads();
    int nl = tid >> 6;
    int c = tid & 63;
    for (int it = 0; it < 4; ++it) {
        int n = blockIdx.x * 16 + it * 4 + nl;
        if (n < NN) {
            const float* wr = wef + (size_t)n * 64;
            float acc = 0.f;
#pragma unroll
            for (int d = 0; d < 64; ++d) acc += wr[d] * Ws[d * 64 + c];
            float val = av[(size_t)n * 64 + c] + acc + s2[(size_t)n * 64 + c];
            out[(size_t)n * 64 + c] = val;
        }
    }
}

extern "C" void kernel_launch(void* const* d_in, const int* in_sizes, int n_in,
                              void* d_out, int out_size, void* d_ws, size_t ws_size,
                              hipStream_t stream) {
    (void)in_sizes; (void)n_in; (void)out_size; (void)ws_size;
    const int* eidx = (const int*)d_in[2];
    const int* src = eidx;
    const int* dst = eidx + EE;

    char* p = (char*)d_ws;
    auto alloc = [&](size_t bytes) {
        void* r = (void*)p;
        p += (bytes + 255) & ~(size_t)255;
        return r;
    };
    unsigned short* wts = (unsigned short*)alloc(111360 * 2);
    int* flags          = (int*)alloc(256);
    int* rowptr         = (int*)alloc((size_t)(NN + 1) * 4);
    int* cntfill        = (int*)alloc((size_t)(NN + 1) * 4);
    int* perm           = (int*)alloc((size_t)EE * 4);      // -> dst_perm after ega1
    int* srcp           = (int*)alloc((size_t)EE * 4);
    unsigned short* efperm = (unsigned short*)alloc((size_t)EE * 64 * 2);  // 204.8MB
    float* alphab       = (float*)alloc((size_t)EE * 4 * 4);  // 25.6MB; l2: alpha2
    unsigned short* q1  = (unsigned short*)alloc((size_t)NN * 128 * 2);  // l2: q2
    unsigned short* k1  = (unsigned short*)alloc((size_t)NN * 128 * 2);  // -> h
    unsigned short* v1  = (unsigned short*)alloc((size_t)NN * 128 * 2);  // l2: k2|v2
    float* qe           = (float*)alloc((size_t)NN * 256 * 4);  // -> s1 -> s2
    float* av           = (float*)alloc((size_t)NN * 128 * 4);  // l2: qe2 | av2
    float* wef          = (float*)alloc((size_t)NN * 256 * 4);  // l2: wef2

    // weight table (d_in indices 3..20, canonical bf16 in ws)
    WTab tab;
    int off = 0;
    const int wsz[18] = {16384, 128, 16384, 128, 16384, 128, 8192, 16384, 128,
                         8192, 64, 8192, 64, 8192, 64, 4096, 8192, 64};
    int offs[18];
    for (int i = 0; i < 18; ++i) {
        tab.p[i] = d_in[3 + i];
        tab.sz[i] = wsz[i];
        tab.off[i] = off;
        offs[i] = off;
        off += wsz[i];
    }
    const unsigned short* Wq1c = wts + offs[0];
    const unsigned short* bq1c = wts + offs[1];
    const unsigned short* Wk1c = wts + offs[2];
    const unsigned short* bk1c = wts + offs[3];
    const unsigned short* Wv1c = wts + offs[4];
    const unsigned short* bv1c = wts + offs[5];
    const unsigned short* We1c = wts + offs[6];
    const unsigned short* Ws1c = wts + offs[7];
    const unsigned short* bs1c = wts + offs[8];
    const unsigned short* Wq2c = wts + offs[9];
    const unsigned short* bq2c = wts + offs[10];
    const unsigned short* Wk2c = wts + offs[11];
    const unsigned short* bk2c = wts + offs[12];
    const unsigned short* Wv2c = wts + offs[13];
    const unsigned short* bv2c = wts + offs[14];
    const unsigned short* We2c = wts + offs[15];
    const unsigned short* Ws2c = wts + offs[16];
    const unsigned short* bs2c = wts + offs[17];

    hipMemsetAsync(cntfill, 0, (size_t)(NN + 1) * 4, stream);
    sniff_kernel<<<1, 64, 0, stream>>>(d_in[3], flags);
    convert_kernel<<<dim3(64, 18), 256, 0, stream>>>(tab, flags, wts);
    count_kernel<<<EE / 256, 256, 0, stream>>>(dst, cntfill);
    scan_kernel<<<1, 1024, 0, stream>>>(cntfill, rowptr);
    fill_kernel<<<EE / 256, 256, 0, stream>>>(dst, cntfill, perm);

    // ---- layer 1 ----
    int g1 = (NN + 31) / 32;
    int gE = (EE + 15) / 16;
    gemm_node<unsigned short, 128, 128, 32, 0><<<g1, 256, 0, stream>>>(d_in[0], flags, Wq1c, bq1c, q1, NN, 128, 1, 0);
    gemm_node<unsigned short, 128, 128, 32, 0><<<g1, 256, 0, stream>>>(d_in[0], flags, Wk1c, bk1c, k1, NN, 128, 1, 0);
    gemm_node<unsigned short, 128, 128, 32, 3><<<g1, 256, 0, stream>>>(d_in[0], flags, Wv1c, bv1c, v1, NN, 0, 0, 0);
    qe1_kernel<<<(NN + 7) / 8, 256, 0, stream>>>(q1, We1c, qe);
    ega1_kernel<<<gE, 256, 0, stream>>>(perm, src, dst, d_in[1], flags, q1, k1, qe,
                                        srcp, efperm, alphab);
    node_accum1<<<(NN + 3) / 4, 256, 0, stream>>>(rowptr, srcp, alphab,
                                                  (const unsigned*)v1, efperm, av, wef);
    float* s1 = qe;  // qe dead after ega1
    gemm_node<float, 128, 128, 32, 0><<<g1, 256, 0, stream>>>(d_in[0], flags, Ws1c, bs1c, s1, NN, 128, 1, 0);
    unsigned short* h = k1;  // k1 dead after ega1
    ep1_kernel<<<(NN + 15) / 16, 256, 0, stream>>>(av, wef, s1, We1c, h);

    // ---- layer 2 (reuses layer-1 buffers) ----
    unsigned short* q2 = q1;
    unsigned short* k2 = v1;                       // v1 dead after node_accum1
    unsigned short* v2 = v1 + (size_t)NN * 64;
    float* s2 = qe;
    float* qe2 = av;                               // av dead after ep1
    float* av2 = av + (size_t)NN * 64;
    float* wef2 = wef;
    float* alpha2 = alphab;
    int g2 = (NN + 63) / 64;
    gemm_node<unsigned short, 128, 64, 64, 0><<<g2, 256, 0, stream>>>(h, flags + 1, Wq2c, bq2c, q2, NN, 64, 1, 0);
    gemm_node<unsigned short, 128, 64, 64, 0><<<g2, 256, 0, stream>>>(h, flags + 1, Wk2c, bk2c, k2, NN, 64, 1, 0);
    gemm_node<unsigned short, 128, 64, 64, 0><<<g2, 256, 0, stream>>>(h, flags + 1, Wv2c, bv2c, v2, NN, 64, 1, 0);
    gemm_node<float, 128, 64, 64, 0><<<g2, 256, 0, stream>>>(h, flags + 1, Ws2c, bs2c, s2, NN, 64, 1, 0);
    qe2_kernel<<<(NN + 3) / 4, 256, 0, stream>>>(q2, We2c, qe2);
    ega2_kernel<<<gE, 256, 0, stream>>>(srcp, perm, q2, k2, qe2, efperm, alpha2);
    node_accum2<<<(NN + 3) / 4, 256, 0, stream>>>(rowptr, srcp, alpha2, v2, efperm,
                                                  av2, wef2);
    ep2_kernel<<<(NN + 15) / 16, 256, 0, stream>>>(av2, wef2, s2, We2c,
                                                   (float*)d_out);
}